// Round 6
// baseline (1484.481 us; speedup 1.0000x reference)
//
#include <hip/hip_runtime.h>

// FP16(pulse bits, 16 floats of 0/1) -> FP8 E4M3 (pulse bits, 8 floats of 0/1).
// Memory-bound: 1.074 GB in + 0.537 GB out per call, HBM floor ~256 us.
//
// R5: unroll x4 with block-strided indices. Each thread issues 4 independent
// dwordx4 loads (64 B in flight; R4 had 16 B) -- every vmem instruction is
// still perfectly wave-contiguous (lane i reads base+i within the instruction).
// The 4 per-item nibbles are packed into ONE 32-bit word so the 4-lane
// butterfly transpose costs 2 shuffles total (SIMD-within-register per-byte
// combines) instead of 8 -- shorter lgkmcnt chain between load and store.
//
// Lane mapping (within a 4-lane group, p = tid&3): lane p holds uint4 part p
// of item k for 4 different items j=0..3 (byte j of the packed word).

typedef unsigned int u32;
typedef u32 u32x4 __attribute__((ext_vector_type(4)));
typedef u32 u32x2 __attribute__((ext_vector_type(2)));

__device__ __forceinline__ u32 convert_word(u32 word) {
    // word = 16-bit fp16 pulse, MSB-first [S,E4..E0,M9..M0]; returns 8-bit
    // fp8 byte MSB-first [S,e3..e0,m2..m0].
    const u32 s = word >> 15;
    const u32 e = (word >> 10) & 31u;
    const u32 m = word & 1023u;

    // normal path: RNE(m >> 7), exponent bump on mantissa carry
    const u32 keep_n   = m >> 7;
    const u32 rbit_n   = (m >> 6) & 1u;
    const u32 sticky_n = (m & 63u) ? 1u : 0u;
    const u32 mant_r   = keep_n + (rbit_n & (sticky_n | (keep_n & 1u)));
    const u32 norm_e   = (e - 8u) + (mant_r >> 3);
    const u32 norm_m   = mant_r & 7u;

    // subnormal path: RNE((1024 + m) >> clip(16-e, 8, 11))
    u32 k = 16u - e;
    k = k < 8u ? 8u : (k > 11u ? 11u : k);
    const u32 x        = 1024u + m;
    const u32 keep_s   = x >> k;
    const u32 rbit_s   = (x >> (k - 1u)) & 1u;
    const u32 sticky_s = (x & ((1u << (k - 1u)) - 1u)) ? 1u : 0u;
    const u32 m_sub    = keep_s + (rbit_s & (sticky_s | (keep_s & 1u)));
    const u32 sub_e    = m_sub >> 3;
    const u32 sub_m    = (m_sub >= 8u) ? 0u : m_sub;

    const u32 out_e = (e > 22u) ? 15u : (e < 5u) ? 0u : (e <= 8u) ? sub_e : norm_e;
    const u32 out_m = (e > 22u) ? 6u  : (e < 5u) ? 0u : (e <= 8u) ? sub_m : norm_m;
    return (s << 7) | (out_e << 3) | out_m;
}

__global__ __launch_bounds__(256) void fp16_to_fp8_pulse_kernel(
    const u32x4* __restrict__ in,   // one uint4 = 4 pulse bits (quarter item)
    u32x2* __restrict__ out)        // one uint2 = 2 output pulse words
{
    const int tid  = (int)threadIdx.x;
    const int base = (int)blockIdx.x * (256 * 4) + tid;
    const u32 p    = (u32)(tid & 3);

    // 4 independent wave-contiguous loads (grid divides exactly; no guard)
    const u32x4 v0 = in[base        ];
    const u32x4 v1 = in[base +  256 ];
    const u32x4 v2 = in[base +  512 ];
    const u32x4 v3 = in[base +  768 ];

#define NIB(v) (((((v).x >> 23) & 1u) << 3) | ((((v).y >> 23) & 1u) << 2) | \
                ((((v).z >> 23) & 1u) << 1) |  (((v).w >> 23) & 1u))
    // byte j of P = this lane's nibble for item j
    const u32 P = NIB(v0) | (NIB(v1) << 8) | (NIB(v2) << 16) | (NIB(v3) << 24);
#undef NIB

    // butterfly step 1 (lane^1): per-byte nibble combine, even part high
    const u32 O1 = (u32)__shfl_xor((int)P, 1);
    const u32 B  = (p & 1u) ? ((O1 << 4) | P) : ((P << 4) | O1);

    // butterfly step 2 (lane^2): per-byte -> per-16-bit-word combine
    const u32 O2 = (u32)__shfl_xor((int)B, 2);
    const u32 Bex01 = (B  & 0xFFu) | ((B  & 0xFF00u) << 8);   // j0 @[7:0], j1 @[23:16]
    const u32 Oex01 = (O2 & 0xFFu) | ((O2 & 0xFF00u) << 8);
    const u32 Bex23 = ((B  >> 16) & 0xFFu) | ((B  >> 8) & 0xFF0000u);
    const u32 Oex23 = ((O2 >> 16) & 0xFFu) | ((O2 >> 8) & 0xFF0000u);
    const u32 W01 = (p & 2u) ? ((Oex01 << 8) | Bex01) : ((Bex01 << 8) | Oex01);
    const u32 W23 = (p & 2u) ? ((Oex23 << 8) | Bex23) : ((Bex23 << 8) | Oex23);

    const u32 w0 = W01 & 0xFFFFu, w1 = W01 >> 16;
    const u32 w2 = W23 & 0xFFFFu, w3 = W23 >> 16;

    const u32 hs = 7u - 2u * p;   // this lane's high output bit index
#define EMIT(word, idx)                                                  \
    {                                                                    \
        const u32 ob = convert_word(word);                               \
        u32x2 o;                                                         \
        o.x = (0u - ((ob >> hs) & 1u))        & 0x3F800000u;             \
        o.y = (0u - ((ob >> (hs - 1u)) & 1u)) & 0x3F800000u;             \
        out[idx] = o;                                                    \
    }
    EMIT(w0, base);
    EMIT(w1, base + 256);
    EMIT(w2, base + 512);
    EMIT(w3, base + 768);
#undef EMIT
}

extern "C" void kernel_launch(void* const* d_in, const int* in_sizes, int n_in,
                              void* d_out, int out_size, void* d_ws, size_t ws_size,
                              hipStream_t stream) {
    const u32x4* in = (const u32x4*)d_in[0];
    u32x2* out = (u32x2*)d_out;

    const int n4 = in_sizes[0] / 4;        // 67,108,864 uint4s
    const int block = 256;
    const int grid = n4 / (block * 4);     // 65,536 blocks (divides exactly)

    fp16_to_fp8_pulse_kernel<<<grid, block, 0, stream>>>(in, out);
}